// Round 1
// baseline (2041.583 us; speedup 1.0000x reference)
//
#include <hip/hip_runtime.h>
#include <hip/hip_bf16.h>
#include <hip/hip_cooperative_groups.h>

namespace cg = cooperative_groups;

#define S_ 64
#define B_ 32
#define H_ 1024
#define E_ 512
#define V_ 32000

typedef unsigned short ushort_t;
typedef __attribute__((ext_vector_type(8))) short short8;
typedef __attribute__((ext_vector_type(4))) float f32x4;

__device__ __forceinline__ ushort_t f32_bf16(float x) {
    union { float f; unsigned u; } v; v.f = x;
    unsigned r = v.u + 0x7FFF + ((v.u >> 16) & 1);   // RNE
    return (ushort_t)(r >> 16);
}

__device__ __forceinline__ float bf16_f32(ushort_t x) {
    union { unsigned u; float f; } v; v.u = ((unsigned)x) << 16;
    return v.f;
}

// ---------------- fp32 -> bf16 convert (vectorized, grid-stride) --------------
__global__ void cvt_bf16(const float* __restrict__ src, ushort_t* __restrict__ dst, int n4) {
    int i = blockIdx.x * blockDim.x + threadIdx.x;
    int stride = gridDim.x * blockDim.x;
    const float4* s4 = (const float4*)src;
    ushort4* d4 = (ushort4*)dst;
    for (; i < n4; i += stride) {
        float4 v = s4[i];
        ushort4 o;
        o.x = f32_bf16(v.x); o.y = f32_bf16(v.y);
        o.z = f32_bf16(v.z); o.w = f32_bf16(v.w);
        d4[i] = o;
    }
}

// ---------------- init hidden: fp32 [2,B,H] -> bf16 double-buffers (slot 1) ---
__global__ void init_hidden(const float* __restrict__ hid,
                            ushort_t* __restrict__ h0buf, ushort_t* __restrict__ h1buf) {
    int i = blockIdx.x * blockDim.x + threadIdx.x;  // 0 .. 2*B*H-1
    int j = i & (B_ * H_ - 1);
    if (i < B_ * H_) h0buf[B_ * H_ + j] = f32_bf16(hid[i]);
    else             h1buf[B_ * H_ + j] = f32_bf16(hid[i]);
}

// ---------------- embedding gather -> bf16 X [S*B, E] -------------------------
__global__ void gather_emb(const int* __restrict__ tok, const float* __restrict__ emb,
                           ushort_t* __restrict__ xb) {
    int m = blockIdx.x;                  // 0..S*B-1
    int t = tok[m];
    const float4* src = (const float4*)(emb + (long)t * E_);
    ushort4* dst = (ushort4*)(xb + (long)m * E_);
    int i = threadIdx.x;                 // blockDim = 128 = E/4
    float4 v = src[i];
    ushort4 o;
    o.x = f32_bf16(v.x); o.y = f32_bf16(v.y);
    o.z = f32_bf16(v.z); o.w = f32_bf16(v.w);
    dst[i] = o;
}

// ---------------- xproj = X @ Wx0^T + bh0  (fp32 out, [S*B, H]) ---------------
__global__ __launch_bounds__(256) void xproj_kernel(const ushort_t* __restrict__ Xb,
                                                    const ushort_t* __restrict__ Wx0b,
                                                    const float* __restrict__ bh0,
                                                    float* __restrict__ xproj) {
    int wid = (blockIdx.x * 256 + threadIdx.x) >> 6;  // 0..8191
    int lane = threadIdx.x & 63;
    int quad = lane >> 4;
    int nt = wid & 63, mt = wid >> 6;                 // mt 0..127, nt 0..63
    int mrow = mt * 16 + (lane & 15);
    int nrow = nt * 16 + (lane & 15);
    const short8* Ap = (const short8*)(Xb + (long)mrow * E_ + quad * 8);
    const short8* Bp = (const short8*)(Wx0b + (long)nrow * E_ + quad * 8);
    f32x4 acc = {0.f, 0.f, 0.f, 0.f};
#pragma unroll
    for (int k = 0; k < E_ / 32; ++k)
        acc = __builtin_amdgcn_mfma_f32_16x16x32_bf16(Ap[k * 4], Bp[k * 4], acc, 0, 0, 0);
    float bias = bh0[nrow];
#pragma unroll
    for (int r = 0; r < 4; ++r) {
        int m = mt * 16 + quad * 4 + r;
        xproj[(long)m * H_ + nrow] = acc[r] + bias;
    }
}

// ---------------- persistent pipelined recurrence (single cooperative launch) -
// 64 blocks x 256 threads. Phase p: blocks 0..31 do layer0(t=p),
// blocks 32..63 do layer1(t=p-1). grid.sync() between phases replaces 65
// kernel launches (+ their per-dispatch L2 acquire/release flushes).
__global__ __launch_bounds__(256) void rnn_steps(const ushort_t* __restrict__ Wh0b,
                                                 const ushort_t* __restrict__ Wx1b,
                                                 const ushort_t* __restrict__ Wh1b,
                                                 const float* __restrict__ bh1,
                                                 const float* __restrict__ xproj,
                                                 ushort_t* __restrict__ h0buf,
                                                 ushort_t* __restrict__ h1buf,
                                                 ushort_t* __restrict__ tops) {
    cg::grid_group grid = cg::this_grid();
    const int lb = blockIdx.x;           // 0..63
    const int lane = threadIdx.x & 63;
    const int widx = threadIdx.x >> 6;
    const int quad = lane >> 4;
    const int wid = (lb & 31) * 4 + widx;     // 0..127 within the layer
    const int nt = wid & 63, mt = wid >> 6;
    const int b0 = mt * 16 + (lane & 15);
    const int h = nt * 16 + (lane & 15);
    const bool is_l0 = (lb < 32);

    const short8* Wp  = (const short8*)(Wh0b + (long)h * H_ + quad * 8);  // layer0 Wh0
    const short8* Wp0 = (const short8*)(Wx1b + (long)h * H_ + quad * 8);  // layer1 Wx1
    const short8* Wp1 = (const short8*)(Wh1b + (long)h * H_ + quad * 8);  // layer1 Wh1
    const float bias1 = bh1[h];

    for (int p = 0; p <= S_; ++p) {
        if (is_l0) {
            // ---- layer 0, t=p: h0[p] = tanh(xproj[p] + h0[p-1] @ Wh0^T)
            if (p < S_) {
                const ushort_t* Aprev = h0buf + ((p + 1) & 1) * (B_ * H_);
                const short8* Ap = (const short8*)(Aprev + (long)b0 * H_ + quad * 8);
                f32x4 acc = {0.f, 0.f, 0.f, 0.f};
#pragma unroll
                for (int k = 0; k < H_ / 32; ++k)
                    acc = __builtin_amdgcn_mfma_f32_16x16x32_bf16(Ap[k * 4], Wp[k * 4], acc, 0, 0, 0);
                ushort_t* out = h0buf + (p & 1) * (B_ * H_);
                const float* xp = xproj + (long)p * B_ * H_;
#pragma unroll
                for (int r = 0; r < 4; ++r) {
                    int b = mt * 16 + quad * 4 + r;
                    float v = tanhf(acc[r] + xp[b * H_ + h]);
                    out[b * H_ + h] = f32_bf16(v);
                }
            }
        } else {
            // ---- layer 1, t=p-1: h1[t] = tanh(h0[t]@Wx1^T + h1[t-1]@Wh1^T + bh1)
            if (p >= 1) {
                int t = p - 1;
                const ushort_t* A0 = h0buf + (t & 1) * (B_ * H_);        // h0[t]
                const ushort_t* A1 = h1buf + ((t + 1) & 1) * (B_ * H_);  // h1[t-1]
                const short8* Ap0 = (const short8*)(A0 + (long)b0 * H_ + quad * 8);
                const short8* Ap1 = (const short8*)(A1 + (long)b0 * H_ + quad * 8);
                f32x4 acc = {0.f, 0.f, 0.f, 0.f};
#pragma unroll
                for (int k = 0; k < H_ / 32; ++k)
                    acc = __builtin_amdgcn_mfma_f32_16x16x32_bf16(Ap0[k * 4], Wp0[k * 4], acc, 0, 0, 0);
#pragma unroll
                for (int k = 0; k < H_ / 32; ++k)
                    acc = __builtin_amdgcn_mfma_f32_16x16x32_bf16(Ap1[k * 4], Wp1[k * 4], acc, 0, 0, 0);
                ushort_t* out = h1buf + (t & 1) * (B_ * H_);
                ushort_t* top = tops + (long)t * B_ * H_;
#pragma unroll
                for (int r = 0; r < 4; ++r) {
                    int b = mt * 16 + quad * 4 + r;
                    float v = tanhf(acc[r] + bias1);
                    ushort_t bv = f32_bf16(v);
                    out[b * H_ + h] = bv;
                    top[b * H_ + h] = bv;
                }
            }
        }
        if (p < S_) grid.sync();
    }
}

// ---------------- final GEMM: logits = tops @ Wout^T + bout -------------------
// m97-style: 128x128 block tile, BK=32, 4 waves each computing 64x64 (4x4 frags)
// 1D grid of 4000 with bijective XCD swizzle: each Wout panel (nblk) is consumed
// by 16 blocks on the SAME XCD -> panel fetched once, not once per XCD.
#define BM 128
#define BN 128
#define BK 32

__device__ __forceinline__ void ld_lds16(const ushort_t* g, ushort_t* l) {
    __builtin_amdgcn_global_load_lds((const __attribute__((address_space(1))) void*)g,
                                     (__attribute__((address_space(3))) void*)l, 16, 0, 0);
}

__global__ __launch_bounds__(256) void out_gemm(const ushort_t* __restrict__ A,   // [2048,1024]
                                                const ushort_t* __restrict__ Bw,  // [32000,1024]
                                                const float* __restrict__ bout,
                                                float* __restrict__ C) {
    __shared__ __align__(16) ushort_t lA[BM * BK];  // 8KB
    __shared__ __align__(16) ushort_t lB[BN * BK];  // 8KB
    // XCD-aware swizzle: 4000 blocks, 8 XCDs, 500 per XCD (4000%8==0, bijective)
    int orig = blockIdx.x;
    int wgid = (orig & 7) * 500 + (orig >> 3);
    int mblk = wgid & 15;    // 0..15
    int nblk = wgid >> 4;    // 0..249
    int tid = threadIdx.x;
    int lane = tid & 63;
    int w = tid >> 6;
    int quad = lane >> 4;
    // staging map: thread tid covers (row = tid/4, k = (tid%4)*8)
    int srow = tid >> 2;
    int skol = (tid & 3) * 8;
    const ushort_t* Ag = A + (long)(mblk * BM + srow) * H_ + skol;
    const ushort_t* Bg = Bw + (long)(nblk * BN + srow) * H_ + skol;
    ushort_t* lA0 = lA + tid * 8;
    ushort_t* lA1 = lA + 2048 + tid * 8;
    ushort_t* lB0 = lB + tid * 8;
    ushort_t* lB1 = lB + 2048 + tid * 8;

    int msub = (w & 1) * 64;
    int nsub = (w >> 1) * 64;
    f32x4 acc[4][4];
#pragma unroll
    for (int i = 0; i < 4; ++i)
#pragma unroll
        for (int j = 0; j < 4; ++j) acc[i][j] = (f32x4){0.f, 0.f, 0.f, 0.f};

    for (int k0 = 0; k0 < H_; k0 += BK) {
        ld_lds16(Ag + k0, lA0);
        ld_lds16(Ag + 64 * H_ + k0, lA1);
        ld_lds16(Bg + k0, lB0);
        ld_lds16(Bg + 64 * H_ + k0, lB1);
        __syncthreads();
        short8 af[4], bf[4];
#pragma unroll
        for (int i = 0; i < 4; ++i)
            af[i] = *(const short8*)&lA[(msub + i * 16 + (lane & 15)) * BK + quad * 8];
#pragma unroll
        for (int j = 0; j < 4; ++j)
            bf[j] = *(const short8*)&lB[(nsub + j * 16 + (lane & 15)) * BK + quad * 8];
#pragma unroll
        for (int i = 0; i < 4; ++i)
#pragma unroll
            for (int j = 0; j < 4; ++j)
                acc[i][j] = __builtin_amdgcn_mfma_f32_16x16x32_bf16(af[i], bf[j], acc[i][j], 0, 0, 0);
        __syncthreads();
    }

#pragma unroll
    for (int j = 0; j < 4; ++j) {
        int n = nblk * BN + nsub + j * 16 + (lane & 15);
        float bo = bout[n];
#pragma unroll
        for (int i = 0; i < 4; ++i) {
#pragma unroll
            for (int r = 0; r < 4; ++r) {
                int m = mblk * BM + msub + i * 16 + quad * 4 + r;
                C[(long)m * V_ + n] = acc[i][j][r] + bo;
            }
        }
    }
}

// ---------------- final hidden: bf16 slot-1 buffers -> fp32 tail of d_out -----
__global__ void final_hidden(const ushort_t* __restrict__ h0buf,
                             const ushort_t* __restrict__ h1buf,
                             float* __restrict__ out) {
    int i = blockIdx.x * blockDim.x + threadIdx.x;  // 0 .. 2*B*H-1
    int j = i & (B_ * H_ - 1);
    // h0[63] lives in h0buf slot (63&1)=1 ; h1[63] in h1buf slot 1
    ushort_t v = (i < B_ * H_) ? h0buf[B_ * H_ + j] : h1buf[B_ * H_ + j];
    out[(long)S_ * B_ * V_ + i] = bf16_f32(v);
}

extern "C" void kernel_launch(void* const* d_in, const int* in_sizes, int n_in,
                              void* d_out, int out_size, void* d_ws, size_t ws_size,
                              hipStream_t stream) {
    const int*   tok  = (const int*)d_in[0];
    const float* hid  = (const float*)d_in[1];
    const float* emb  = (const float*)d_in[2];
    const float* Wx0  = (const float*)d_in[3];
    const float* Wh0  = (const float*)d_in[4];
    const float* bh0  = (const float*)d_in[5];
    const float* Wx1  = (const float*)d_in[6];
    const float* Wh1  = (const float*)d_in[7];
    const float* bh1  = (const float*)d_in[8];
    const float* Wout = (const float*)d_in[9];
    const float* bout = (const float*)d_in[10];
    float* out = (float*)d_out;

    char* ws = (char*)d_ws;
    size_t off = 0;
    ushort_t* woutb = (ushort_t*)(ws + off); off += (size_t)V_ * H_ * 2;       // 65,536,000
    ushort_t* wh0b  = (ushort_t*)(ws + off); off += (size_t)H_ * H_ * 2;       // 2MB
    ushort_t* wx1b  = (ushort_t*)(ws + off); off += (size_t)H_ * H_ * 2;
    ushort_t* wh1b  = (ushort_t*)(ws + off); off += (size_t)H_ * H_ * 2;
    ushort_t* wx0b  = (ushort_t*)(ws + off); off += (size_t)H_ * E_ * 2;       // 1MB
    ushort_t* xb    = (ushort_t*)(ws + off); off += (size_t)S_ * B_ * E_ * 2;  // 2MB
    float*    xproj = (float*)(ws + off);    off += (size_t)S_ * B_ * H_ * 4;  // 8MB
    ushort_t* topsb = (ushort_t*)(ws + off); off += (size_t)S_ * B_ * H_ * 2;  // 4MB
    ushort_t* h0b   = (ushort_t*)(ws + off); off += (size_t)2 * B_ * H_ * 2;
    ushort_t* h1b   = (ushort_t*)(ws + off); off += (size_t)2 * B_ * H_ * 2;

    // weight conversions (independent, back-to-back on stream)
    cvt_bf16<<<2048, 256, 0, stream>>>(Wout, woutb, V_ * H_ / 4);
    cvt_bf16<<<256, 256, 0, stream>>>(Wh0, wh0b, H_ * H_ / 4);
    cvt_bf16<<<256, 256, 0, stream>>>(Wx1, wx1b, H_ * H_ / 4);
    cvt_bf16<<<256, 256, 0, stream>>>(Wh1, wh1b, H_ * H_ / 4);
    cvt_bf16<<<128, 256, 0, stream>>>(Wx0, wx0b, H_ * E_ / 4);
    init_hidden<<<256, 256, 0, stream>>>(hid, h0b, h1b);
    gather_emb<<<S_ * B_, 128, 0, stream>>>(tok, emb, xb);
    // x-side projection for all timesteps, one GEMM
    xproj_kernel<<<2048, 256, 0, stream>>>(xb, wx0b, bh0, xproj);
    // pipelined recurrence: ONE cooperative launch, grid.sync() between phases
    {
        void* args[] = {(void*)&wh0b, (void*)&wx1b, (void*)&wh1b, (void*)&bh1,
                        (void*)&xproj, (void*)&h0b, (void*)&h1b, (void*)&topsb};
        hipLaunchCooperativeKernel((const void*)rnn_steps, dim3(64), dim3(256), args, 0u, stream);
    }
    // output projection (XCD-swizzled 1D grid)
    out_gemm<<<4000, 256, 0, stream>>>(topsb, woutb, bout, out);
    final_hidden<<<256, 256, 0, stream>>>(h0b, h1b, out);
}

// Round 3
// 1568.858 us; speedup vs baseline: 1.3013x; 1.3013x over previous
//
#include <hip/hip_runtime.h>
#include <hip/hip_bf16.h>

#define S_ 64
#define B_ 32
#define H_ 1024
#define E_ 512
#define V_ 32000

typedef unsigned short ushort_t;
typedef __attribute__((ext_vector_type(8))) short short8;
typedef __attribute__((ext_vector_type(4))) float f32x4;

__device__ __forceinline__ ushort_t f32_bf16(float x) {
    union { float f; unsigned u; } v; v.f = x;
    unsigned r = v.u + 0x7FFF + ((v.u >> 16) & 1);   // RNE
    return (ushort_t)(r >> 16);
}

__device__ __forceinline__ float bf16_f32(ushort_t x) {
    union { unsigned u; float f; } v; v.u = ((unsigned)x) << 16;
    return v.f;
}

// ================= coherent (device-scope, L2-bypass) memory helpers =========
// sc0 sc1 ops are serviced at the memory-side Infinity Cache (the device
// coherence point) -> no buffer_wbl2/buffer_inv bulk fences needed per phase.
// NOTE gfx950 asm syntax: offset: immediate must PRECEDE cache-policy flags.

#define WAITV asm volatile("s_waitcnt vmcnt(0)" ::: "memory")
#define SB    __builtin_amdgcn_sched_barrier(0)

// issue 16 coherent 16B loads (no wait inside; caller does WAITV; SB)
__device__ __forceinline__ void ld16n(short8* a, const ushort_t* p) {
    asm volatile(
        "global_load_dwordx4 %0, %16, off offset:0 sc0 sc1\n\t"
        "global_load_dwordx4 %1, %16, off offset:64 sc0 sc1\n\t"
        "global_load_dwordx4 %2, %16, off offset:128 sc0 sc1\n\t"
        "global_load_dwordx4 %3, %16, off offset:192 sc0 sc1\n\t"
        "global_load_dwordx4 %4, %16, off offset:256 sc0 sc1\n\t"
        "global_load_dwordx4 %5, %16, off offset:320 sc0 sc1\n\t"
        "global_load_dwordx4 %6, %16, off offset:384 sc0 sc1\n\t"
        "global_load_dwordx4 %7, %16, off offset:448 sc0 sc1\n\t"
        "global_load_dwordx4 %8, %16, off offset:512 sc0 sc1\n\t"
        "global_load_dwordx4 %9, %16, off offset:576 sc0 sc1\n\t"
        "global_load_dwordx4 %10, %16, off offset:640 sc0 sc1\n\t"
        "global_load_dwordx4 %11, %16, off offset:704 sc0 sc1\n\t"
        "global_load_dwordx4 %12, %16, off offset:768 sc0 sc1\n\t"
        "global_load_dwordx4 %13, %16, off offset:832 sc0 sc1\n\t"
        "global_load_dwordx4 %14, %16, off offset:896 sc0 sc1\n\t"
        "global_load_dwordx4 %15, %16, off offset:960 sc0 sc1"
        : "=&v"(a[0]), "=&v"(a[1]), "=&v"(a[2]), "=&v"(a[3]),
          "=&v"(a[4]), "=&v"(a[5]), "=&v"(a[6]), "=&v"(a[7]),
          "=&v"(a[8]), "=&v"(a[9]), "=&v"(a[10]), "=&v"(a[11]),
          "=&v"(a[12]), "=&v"(a[13]), "=&v"(a[14]), "=&v"(a[15])
        : "v"(p));
}

__device__ __forceinline__ void st2_coh(ushort_t* p, unsigned v) {
    asm volatile("global_store_short %0, %1, off sc0 sc1" :: "v"(p), "v"(v) : "memory");
}

// wave-level spin: lane0 polls, whole wave is held by exec-mask divergence
__device__ __forceinline__ void wait_ge(unsigned* c, int tgt) {
    if (tgt <= 0) return;
    if ((threadIdx.x & 63) == 0) {
        int guard = 0;
        while ((int)__hip_atomic_load(c, __ATOMIC_RELAXED, __HIP_MEMORY_SCOPE_AGENT) < tgt &&
               ++guard < (1 << 24))
            __builtin_amdgcn_s_sleep(2);
    }
    __builtin_amdgcn_sched_barrier(0);
}

// drain stores to the coherence point, then fire-and-forget arrival
__device__ __forceinline__ void arrive(unsigned* c) {
    asm volatile("s_waitcnt vmcnt(0)" ::: "memory");
    if ((threadIdx.x & 63) == 0)
        (void)__hip_atomic_fetch_add(c, 1u, __ATOMIC_RELAXED, __HIP_MEMORY_SCOPE_AGENT);
    __builtin_amdgcn_sched_barrier(0);
}

// ---------------- fp32 -> bf16 convert (vectorized, grid-stride) --------------
__global__ void cvt_bf16(const float* __restrict__ src, ushort_t* __restrict__ dst, int n4) {
    int i = blockIdx.x * blockDim.x + threadIdx.x;
    int stride = gridDim.x * blockDim.x;
    const float4* s4 = (const float4*)src;
    ushort4* d4 = (ushort4*)dst;
    for (; i < n4; i += stride) {
        float4 v = s4[i];
        ushort4 o;
        o.x = f32_bf16(v.x); o.y = f32_bf16(v.y);
        o.z = f32_bf16(v.z); o.w = f32_bf16(v.w);
        d4[i] = o;
    }
}

// ---------------- init hidden + zero barrier counters -------------------------
__global__ void init_hidden(const float* __restrict__ hid,
                            ushort_t* __restrict__ h0buf, ushort_t* __restrict__ h1buf,
                            unsigned* __restrict__ ctrs) {
    int i = blockIdx.x * blockDim.x + threadIdx.x;  // 0 .. 2*B*H-1
    int j = i & (B_ * H_ - 1);
    if (i < B_ * H_) h0buf[B_ * H_ + j] = f32_bf16(hid[i]);
    else             h1buf[B_ * H_ + j] = f32_bf16(hid[i]);
    if (blockIdx.x == 0 && threadIdx.x < 64) ctrs[threadIdx.x] = 0;
}

// ---------------- embedding gather -> bf16 X [S*B, E] -------------------------
__global__ void gather_emb(const int* __restrict__ tok, const float* __restrict__ emb,
                           ushort_t* __restrict__ xb) {
    int m = blockIdx.x;                  // 0..S*B-1
    int t = tok[m];
    const float4* src = (const float4*)(emb + (long)t * E_);
    ushort4* dst = (ushort4*)(xb + (long)m * E_);
    int i = threadIdx.x;                 // blockDim = 128 = E/4
    float4 v = src[i];
    ushort4 o;
    o.x = f32_bf16(v.x); o.y = f32_bf16(v.y);
    o.z = f32_bf16(v.z); o.w = f32_bf16(v.w);
    dst[i] = o;
}

// ---------------- xproj = X @ Wx0^T + bh0  (fp32 out, [S*B, H]) ---------------
__global__ __launch_bounds__(256) void xproj_kernel(const ushort_t* __restrict__ Xb,
                                                    const ushort_t* __restrict__ Wx0b,
                                                    const float* __restrict__ bh0,
                                                    float* __restrict__ xproj) {
    int wid = (blockIdx.x * 256 + threadIdx.x) >> 6;  // 0..8191
    int lane = threadIdx.x & 63;
    int quad = lane >> 4;
    int nt = wid & 63, mt = wid >> 6;                 // mt 0..127, nt 0..63
    int mrow = mt * 16 + (lane & 15);
    int nrow = nt * 16 + (lane & 15);
    const short8* Ap = (const short8*)(Xb + (long)mrow * E_ + quad * 8);
    const short8* Bp = (const short8*)(Wx0b + (long)nrow * E_ + quad * 8);
    f32x4 acc = {0.f, 0.f, 0.f, 0.f};
#pragma unroll
    for (int k = 0; k < E_ / 32; ++k)
        acc = __builtin_amdgcn_mfma_f32_16x16x32_bf16(Ap[k * 4], Bp[k * 4], acc, 0, 0, 0);
    float bias = bh0[nrow];
#pragma unroll
    for (int r = 0; r < 4; ++r) {
        int m = mt * 16 + quad * 4 + r;
        xproj[(long)m * H_ + nrow] = acc[r] + bias;
    }
}

// ---------------- persistent pipelined recurrence, custom wave barrier --------
// 64 blocks x 256 thr (normal launch; 64 blocks on 256 CUs are co-resident).
// Counters count WAVE arrivals (128/layer/phase). Weights live in VGPRs.
// h state moves via sc0 sc1 (device-coherent) stores/loads -> no bulk L2 fences.
__global__ __launch_bounds__(256, 1) void rnn_steps2(
        const ushort_t* __restrict__ Wh0b,
        const ushort_t* __restrict__ Wx1b,
        const ushort_t* __restrict__ Wh1b,
        const float* __restrict__ bh1,
        const float* __restrict__ xproj,
        ushort_t* __restrict__ h0buf,
        ushort_t* __restrict__ h1buf,
        ushort_t* __restrict__ tops,
        unsigned* __restrict__ ctrs) {
    const int lb = blockIdx.x;           // 0..63
    const int lane = threadIdx.x & 63;
    const int widx = threadIdx.x >> 6;
    const int quad = lane >> 4;
    const int l15 = lane & 15;
    const int wid = (lb & 31) * 4 + widx;     // 0..127 within layer
    const int nt = wid & 63, mt = wid >> 6;
    const int b0 = mt * 16 + l15;
    const int h = nt * 16 + l15;
    unsigned* l0c = ctrs;        // layer0 wave arrivals (cumulative)
    unsigned* l1c = ctrs + 32;   // layer1 wave arrivals
    constexpr int BH = B_ * H_;

    if (lb < 32) {
        // ======== layer 0: h0[p] = tanh(xproj[p] + h0[p-1] @ Wh0^T) ==========
        short8 wf[32];
        const short8* Wr = (const short8*)(Wh0b + (long)h * H_ + quad * 8);
#pragma unroll
        for (int k = 0; k < 32; ++k) wf[k] = Wr[k * 4];
        for (int p = 0; p < S_; ++p) {
            wait_ge(l0c, 128 * p);                     // h0[p-1] complete
            const float* xp = xproj + (long)p * BH;
            float xv[4];
#pragma unroll
            for (int r = 0; r < 4; ++r) xv[r] = xp[(long)(mt * 16 + quad * 4 + r) * H_ + h];
            const ushort_t* Ap = h0buf + ((p + 1) & 1) * BH + (long)b0 * H_ + quad * 8;
            short8 a[32];
            ld16n(a, Ap);
            ld16n(a + 16, Ap + 512);
            WAITV; SB;
            f32x4 aA = {0.f, 0.f, 0.f, 0.f}, aB = {0.f, 0.f, 0.f, 0.f};
#pragma unroll
            for (int k = 0; k < 32; k += 2) {
                aA = __builtin_amdgcn_mfma_f32_16x16x32_bf16(a[k], wf[k], aA, 0, 0, 0);
                aB = __builtin_amdgcn_mfma_f32_16x16x32_bf16(a[k + 1], wf[k + 1], aB, 0, 0, 0);
            }
            float vv[4];
#pragma unroll
            for (int r = 0; r < 4; ++r) vv[r] = tanhf(aA[r] + aB[r] + xv[r]);
            wait_ge(l1c, 128 * (p - 1));               // WAR: layer1 done reading this slot
            ushort_t* outp = h0buf + (p & 1) * BH;
#pragma unroll
            for (int r = 0; r < 4; ++r)
                st2_coh(outp + (long)(mt * 16 + quad * 4 + r) * H_ + h, (unsigned)f32_bf16(vv[r]));
            arrive(l0c);
        }
    } else {
        // ======== layer 1: h1[t] = tanh(h0[t]@Wx1^T + h1[t-1]@Wh1^T + bh1) ===
        short8 wfx[32], wfh[32];
        const short8* Wxr = (const short8*)(Wx1b + (long)h * H_ + quad * 8);
        const short8* Whr = (const short8*)(Wh1b + (long)h * H_ + quad * 8);
#pragma unroll
        for (int k = 0; k < 32; ++k) { wfx[k] = Wxr[k * 4]; wfh[k] = Whr[k * 4]; }
        const float bias1 = bh1[h];
        for (int p = 1; p <= S_; ++p) {
            const int t = p - 1;
            wait_ge(l0c, 128 * p);                     // h0[t] complete
            wait_ge(l1c, 128 * (p - 1));               // h1[t-1] complete (+ WAR)
            const ushort_t* A0 = h0buf + (t & 1) * BH + (long)b0 * H_ + quad * 8;
            const ushort_t* A1 = h1buf + ((t + 1) & 1) * BH + (long)b0 * H_ + quad * 8;
            f32x4 aA = {0.f, 0.f, 0.f, 0.f}, aB = {0.f, 0.f, 0.f, 0.f};
            {
                short8 a0[16], a1[16];
                ld16n(a0, A0); ld16n(a1, A1);
                WAITV; SB;
#pragma unroll
                for (int k = 0; k < 16; ++k) {
                    aA = __builtin_amdgcn_mfma_f32_16x16x32_bf16(a0[k], wfx[k], aA, 0, 0, 0);
                    aB = __builtin_amdgcn_mfma_f32_16x16x32_bf16(a1[k], wfh[k], aB, 0, 0, 0);
                }
            }
            {
                short8 a0[16], a1[16];
                ld16n(a0, A0 + 512); ld16n(a1, A1 + 512);
                WAITV; SB;
#pragma unroll
                for (int k = 0; k < 16; ++k) {
                    aA = __builtin_amdgcn_mfma_f32_16x16x32_bf16(a0[k], wfx[16 + k], aA, 0, 0, 0);
                    aB = __builtin_amdgcn_mfma_f32_16x16x32_bf16(a1[k], wfh[16 + k], aB, 0, 0, 0);
                }
            }
            ushort_t* outp = h1buf + (t & 1) * BH;
            ushort_t* top = tops + (long)t * BH;
#pragma unroll
            for (int r = 0; r < 4; ++r) {
                float v = tanhf(aA[r] + aB[r] + bias1);
                ushort_t bv = f32_bf16(v);
                st2_coh(outp + (long)(mt * 16 + quad * 4 + r) * H_ + h, (unsigned)bv);
                top[(long)(mt * 16 + quad * 4 + r) * H_ + h] = bv;   // normal store
            }
            arrive(l1c);
        }
    }
}

// ---------------- final GEMM: logits = tops @ Wout^T + bout -------------------
// 128x128 tile, BK=32, 4 waves x 64x64. LDS slot-swizzle (both-sides, rule #21):
// LDS[row][slot] <- global[row][slot ^ ((row>>1)&3)]; read slot = quad ^ ((row>>1)&3).
// Turns the 8-way ds_read_b128 bank conflict into the free 2-way.
#define BM 128
#define BN 128
#define BK 32

__device__ __forceinline__ void ld_lds16(const ushort_t* g, ushort_t* l) {
    __builtin_amdgcn_global_load_lds((const __attribute__((address_space(1))) void*)g,
                                     (__attribute__((address_space(3))) void*)l, 16, 0, 0);
}

__global__ __launch_bounds__(256) void out_gemm(const ushort_t* __restrict__ A,   // [2048,1024]
                                                const ushort_t* __restrict__ Bw,  // [32000,1024]
                                                const float* __restrict__ bout,
                                                float* __restrict__ C) {
    __shared__ __align__(16) ushort_t lA[BM * BK];  // 8KB
    __shared__ __align__(16) ushort_t lB[BN * BK];  // 8KB
    int mblk = blockIdx.x;   // 0..15
    int nblk = blockIdx.y;   // 0..249
    int tid = threadIdx.x;
    int lane = tid & 63;
    int w = tid >> 6;
    int quad = lane >> 4;
    // staging map: thread tid covers (row = tid/4, 16B slot = tid%4), pre-swizzled src
    int srow = tid >> 2;
    int sslot = (tid & 3) ^ ((srow >> 1) & 3);
    int skol = sslot * 8;
    const ushort_t* Ag = A + (long)(mblk * BM + srow) * H_ + skol;
    const ushort_t* Bg = Bw + (long)(nblk * BN + srow) * H_ + skol;
    ushort_t* lA0 = lA + tid * 8;
    ushort_t* lA1 = lA + 2048 + tid * 8;
    ushort_t* lB0 = lB + tid * 8;              // rows 0..63
    ushort_t* lB1 = lB + 2048 + tid * 8;       // rows 64..127 ((row>>1)&3 unchanged by +64)

    int msub = (w & 1) * 64;
    int nsub = (w >> 1) * 64;
    int l15 = lane & 15;
    int rquad = quad ^ ((l15 >> 1) & 3);       // swizzled read slot
    f32x4 acc[4][4];
#pragma unroll
    for (int i = 0; i < 4; ++i)
#pragma unroll
        for (int j = 0; j < 4; ++j) acc[i][j] = (f32x4){0.f, 0.f, 0.f, 0.f};

    for (int k0 = 0; k0 < H_; k0 += BK) {
        ld_lds16(Ag + k0, lA0);
        ld_lds16(Ag + 64 * H_ + k0, lA1);
        ld_lds16(Bg + k0, lB0);
        ld_lds16(Bg + 64 * H_ + k0, lB1);
        __syncthreads();
        short8 af[4], bf[4];
#pragma unroll
        for (int i = 0; i < 4; ++i)
            af[i] = *(const short8*)&lA[(msub + i * 16 + l15) * BK + rquad * 8];
#pragma unroll
        for (int j = 0; j < 4; ++j)
            bf[j] = *(const short8*)&lB[(nsub + j * 16 + l15) * BK + rquad * 8];
#pragma unroll
        for (int i = 0; i < 4; ++i)
#pragma unroll
            for (int j = 0; j < 4; ++j)
                acc[i][j] = __builtin_amdgcn_mfma_f32_16x16x32_bf16(af[i], bf[j], acc[i][j], 0, 0, 0);
        __syncthreads();
    }

#pragma unroll
    for (int j = 0; j < 4; ++j) {
        int n = nblk * BN + nsub + j * 16 + l15;
        float bo = bout[n];
#pragma unroll
        for (int i = 0; i < 4; ++i) {
#pragma unroll
            for (int r = 0; r < 4; ++r) {
                int m = mblk * BM + msub + i * 16 + quad * 4 + r;
                C[(long)m * V_ + n] = acc[i][j][r] + bo;
            }
        }
    }
}

// ---------------- final hidden: bf16 slot-1 buffers -> fp32 tail of d_out -----
__global__ void final_hidden(const ushort_t* __restrict__ h0buf,
                             const ushort_t* __restrict__ h1buf,
                             float* __restrict__ out) {
    int i = blockIdx.x * blockDim.x + threadIdx.x;  // 0 .. 2*B*H-1
    int j = i & (B_ * H_ - 1);
    // h0[63] lives in h0buf slot (63&1)=1 ; h1[63] in h1buf slot 1
    ushort_t v = (i < B_ * H_) ? h0buf[B_ * H_ + j] : h1buf[B_ * H_ + j];
    out[(long)S_ * B_ * V_ + i] = bf16_f32(v);
}

extern "C" void kernel_launch(void* const* d_in, const int* in_sizes, int n_in,
                              void* d_out, int out_size, void* d_ws, size_t ws_size,
                              hipStream_t stream) {
    const int*   tok  = (const int*)d_in[0];
    const float* hid  = (const float*)d_in[1];
    const float* emb  = (const float*)d_in[2];
    const float* Wx0  = (const float*)d_in[3];
    const float* Wh0  = (const float*)d_in[4];
    const float* bh0  = (const float*)d_in[5];
    const float* Wx1  = (const float*)d_in[6];
    const float* Wh1  = (const float*)d_in[7];
    const float* bh1  = (const float*)d_in[8];
    const float* Wout = (const float*)d_in[9];
    const float* bout = (const float*)d_in[10];
    float* out = (float*)d_out;

    char* ws = (char*)d_ws;
    size_t off = 0;
    ushort_t* woutb = (ushort_t*)(ws + off); off += (size_t)V_ * H_ * 2;       // 65,536,000
    ushort_t* wh0b  = (ushort_t*)(ws + off); off += (size_t)H_ * H_ * 2;       // 2MB
    ushort_t* wx1b  = (ushort_t*)(ws + off); off += (size_t)H_ * H_ * 2;
    ushort_t* wh1b  = (ushort_t*)(ws + off); off += (size_t)H_ * H_ * 2;
    ushort_t* wx0b  = (ushort_t*)(ws + off); off += (size_t)H_ * E_ * 2;       // 1MB
    ushort_t* xb    = (ushort_t*)(ws + off); off += (size_t)S_ * B_ * E_ * 2;  // 2MB
    float*    xproj = (float*)(ws + off);    off += (size_t)S_ * B_ * H_ * 4;  // 8MB
    ushort_t* topsb = (ushort_t*)(ws + off); off += (size_t)S_ * B_ * H_ * 2;  // 4MB
    ushort_t* h0b   = (ushort_t*)(ws + off); off += (size_t)2 * B_ * H_ * 2;
    ushort_t* h1b   = (ushort_t*)(ws + off); off += (size_t)2 * B_ * H_ * 2;
    unsigned* ctrs  = (unsigned*)(ws + off); off += 256;

    // weight conversions (independent, back-to-back on stream)
    cvt_bf16<<<2048, 256, 0, stream>>>(Wout, woutb, V_ * H_ / 4);
    cvt_bf16<<<256, 256, 0, stream>>>(Wh0, wh0b, H_ * H_ / 4);
    cvt_bf16<<<256, 256, 0, stream>>>(Wx1, wx1b, H_ * H_ / 4);
    cvt_bf16<<<256, 256, 0, stream>>>(Wh1, wh1b, H_ * H_ / 4);
    cvt_bf16<<<128, 256, 0, stream>>>(Wx0, wx0b, H_ * E_ / 4);
    init_hidden<<<256, 256, 0, stream>>>(hid, h0b, h1b, ctrs);
    gather_emb<<<S_ * B_, 128, 0, stream>>>(tok, emb, xb);
    // x-side projection for all timesteps, one GEMM
    xproj_kernel<<<2048, 256, 0, stream>>>(xb, wx0b, bh0, xproj);
    // persistent pipelined recurrence with custom wave-level barrier
    rnn_steps2<<<64, 256, 0, stream>>>(wh0b, wx1b, wh1b, bh1, xproj, h0b, h1b, topsb, ctrs);
    // output projection
    out_gemm<<<dim3(16, 250), 256, 0, stream>>>(topsb, woutb, bout, out);
    final_hidden<<<256, 256, 0, stream>>>(h0b, h1b, out);
}

// Round 4
// 1424.224 us; speedup vs baseline: 1.4335x; 1.1016x over previous
//
#include <hip/hip_runtime.h>
#include <hip/hip_bf16.h>

#define S_ 64
#define B_ 32
#define H_ 1024
#define E_ 512
#define V_ 32000

typedef unsigned short ushort_t;
typedef __attribute__((ext_vector_type(8))) short short8;
typedef __attribute__((ext_vector_type(4))) float f32x4;

__device__ __forceinline__ ushort_t f32_bf16(float x) {
    union { float f; unsigned u; } v; v.f = x;
    unsigned r = v.u + 0x7FFF + ((v.u >> 16) & 1);   // RNE
    return (ushort_t)(r >> 16);
}

__device__ __forceinline__ float bf16_f32(ushort_t x) {
    union { unsigned u; float f; } v; v.u = ((unsigned)x) << 16;
    return v.f;
}

// ================= coherent (device-scope, L2-bypass) memory helpers =========
// sc0 sc1 ops are serviced at the memory-side Infinity Cache (the device
// coherence point). Barrier = per-wave FLAG WORDS (single-writer stores, no
// atomic RMW contention); consumers poll 128 flags with ONE dwordx4/lane load.

#define WAITV asm volatile("s_waitcnt vmcnt(0)" ::: "memory")
#define SB    __builtin_amdgcn_sched_barrier(0)

// issue 16 coherent 16B loads (no wait inside; caller does WAITV; SB)
__device__ __forceinline__ void ld16n(short8* a, const ushort_t* p) {
    asm volatile(
        "global_load_dwordx4 %0, %16, off offset:0 sc0 sc1\n\t"
        "global_load_dwordx4 %1, %16, off offset:64 sc0 sc1\n\t"
        "global_load_dwordx4 %2, %16, off offset:128 sc0 sc1\n\t"
        "global_load_dwordx4 %3, %16, off offset:192 sc0 sc1\n\t"
        "global_load_dwordx4 %4, %16, off offset:256 sc0 sc1\n\t"
        "global_load_dwordx4 %5, %16, off offset:320 sc0 sc1\n\t"
        "global_load_dwordx4 %6, %16, off offset:384 sc0 sc1\n\t"
        "global_load_dwordx4 %7, %16, off offset:448 sc0 sc1\n\t"
        "global_load_dwordx4 %8, %16, off offset:512 sc0 sc1\n\t"
        "global_load_dwordx4 %9, %16, off offset:576 sc0 sc1\n\t"
        "global_load_dwordx4 %10, %16, off offset:640 sc0 sc1\n\t"
        "global_load_dwordx4 %11, %16, off offset:704 sc0 sc1\n\t"
        "global_load_dwordx4 %12, %16, off offset:768 sc0 sc1\n\t"
        "global_load_dwordx4 %13, %16, off offset:832 sc0 sc1\n\t"
        "global_load_dwordx4 %14, %16, off offset:896 sc0 sc1\n\t"
        "global_load_dwordx4 %15, %16, off offset:960 sc0 sc1"
        : "=&v"(a[0]), "=&v"(a[1]), "=&v"(a[2]), "=&v"(a[3]),
          "=&v"(a[4]), "=&v"(a[5]), "=&v"(a[6]), "=&v"(a[7]),
          "=&v"(a[8]), "=&v"(a[9]), "=&v"(a[10]), "=&v"(a[11]),
          "=&v"(a[12]), "=&v"(a[13]), "=&v"(a[14]), "=&v"(a[15])
        : "v"(p));
}

__device__ __forceinline__ void st2_coh(ushort_t* p, unsigned v) {
    asm volatile("global_store_short %0, %1, off sc0 sc1" :: "v"(p), "v"(v) : "memory");
}

// flags[0..127] = layer0 wave flags, flags[128..255] = layer1 wave flags.
// Wait until all layer0 flags >= tA AND all layer1 flags >= tB.
// Lanes 0..31 poll layer0 (4 flags each), lanes 32..63 poll layer1.
__device__ __forceinline__ void wait2(const unsigned* flags, int tA, int tB) {
    if (tA <= 0 && tB <= 0) return;
    const int lane = threadIdx.x & 63;
    const unsigned* p = flags + lane * 4;
    const int tgt = (lane < 32) ? tA : tB;   // <=0 lanes are trivially satisfied
    for (int it = 0; it < (1 << 22); ++it) {
        uint4 v;
        asm volatile("global_load_dwordx4 %0, %1, off sc0 sc1\n\t"
                     "s_waitcnt vmcnt(0)"
                     : "=v"(v) : "v"(p) : "memory");
        int m = (int)v.x;
        m = m < (int)v.y ? m : (int)v.y;
        m = m < (int)v.z ? m : (int)v.z;
        m = m < (int)v.w ? m : (int)v.w;
        if (__all(m >= tgt)) break;
        __builtin_amdgcn_s_sleep(1);
    }
    __builtin_amdgcn_sched_barrier(0);
}

// drain this wave's stores to the coherence point, then publish completed-phase
// count to this wave's own flag word (single writer -> plain coherent store).
__device__ __forceinline__ void set_flag(unsigned* fl, unsigned val) {
    asm volatile("s_waitcnt vmcnt(0)" ::: "memory");
    if ((threadIdx.x & 63) == 0)
        asm volatile("global_store_dword %0, %1, off sc0 sc1" :: "v"(fl), "v"(val) : "memory");
    __builtin_amdgcn_sched_barrier(0);
}

// ---------------- fp32 -> bf16 convert (vectorized, grid-stride) --------------
__global__ void cvt_bf16(const float* __restrict__ src, ushort_t* __restrict__ dst, int n4) {
    int i = blockIdx.x * blockDim.x + threadIdx.x;
    int stride = gridDim.x * blockDim.x;
    const float4* s4 = (const float4*)src;
    ushort4* d4 = (ushort4*)dst;
    for (; i < n4; i += stride) {
        float4 v = s4[i];
        ushort4 o;
        o.x = f32_bf16(v.x); o.y = f32_bf16(v.y);
        o.z = f32_bf16(v.z); o.w = f32_bf16(v.w);
        d4[i] = o;
    }
}

// ---------------- init hidden + zero barrier flags ----------------------------
__global__ void init_hidden(const float* __restrict__ hid,
                            ushort_t* __restrict__ h0buf, ushort_t* __restrict__ h1buf,
                            unsigned* __restrict__ flags) {
    int i = blockIdx.x * blockDim.x + threadIdx.x;  // 0 .. 2*B*H-1
    int j = i & (B_ * H_ - 1);
    if (i < B_ * H_) h0buf[B_ * H_ + j] = f32_bf16(hid[i]);
    else             h1buf[B_ * H_ + j] = f32_bf16(hid[i]);
    if (blockIdx.x == 0 && threadIdx.x < 256) flags[threadIdx.x] = 0;
}

// ---------------- embedding gather -> bf16 X [S*B, E] -------------------------
__global__ void gather_emb(const int* __restrict__ tok, const float* __restrict__ emb,
                           ushort_t* __restrict__ xb) {
    int m = blockIdx.x;                  // 0..S*B-1
    int t = tok[m];
    const float4* src = (const float4*)(emb + (long)t * E_);
    ushort4* dst = (ushort4*)(xb + (long)m * E_);
    int i = threadIdx.x;                 // blockDim = 128 = E/4
    float4 v = src[i];
    ushort4 o;
    o.x = f32_bf16(v.x); o.y = f32_bf16(v.y);
    o.z = f32_bf16(v.z); o.w = f32_bf16(v.w);
    dst[i] = o;
}

// ---------------- xproj = X @ Wx0^T + bh0  (fp32 out, [S*B, H]) ---------------
__global__ __launch_bounds__(256) void xproj_kernel(const ushort_t* __restrict__ Xb,
                                                    const ushort_t* __restrict__ Wx0b,
                                                    const float* __restrict__ bh0,
                                                    float* __restrict__ xproj) {
    int wid = (blockIdx.x * 256 + threadIdx.x) >> 6;  // 0..8191
    int lane = threadIdx.x & 63;
    int quad = lane >> 4;
    int nt = wid & 63, mt = wid >> 6;                 // mt 0..127, nt 0..63
    int mrow = mt * 16 + (lane & 15);
    int nrow = nt * 16 + (lane & 15);
    const short8* Ap = (const short8*)(Xb + (long)mrow * E_ + quad * 8);
    const short8* Bp = (const short8*)(Wx0b + (long)nrow * E_ + quad * 8);
    f32x4 acc = {0.f, 0.f, 0.f, 0.f};
#pragma unroll
    for (int k = 0; k < E_ / 32; ++k)
        acc = __builtin_amdgcn_mfma_f32_16x16x32_bf16(Ap[k * 4], Bp[k * 4], acc, 0, 0, 0);
    float bias = bh0[nrow];
#pragma unroll
    for (int r = 0; r < 4; ++r) {
        int m = mt * 16 + quad * 4 + r;
        xproj[(long)m * H_ + nrow] = acc[r] + bias;
    }
}

// ---------------- persistent pipelined recurrence, flag-word barrier ----------
// 64 blocks x 256 thr. Per-wave flag words (no atomic RMW contention):
// producer drains stores then writes its completed-phase count; consumers poll
// all 128 flags of a layer with one dwordx4/lane load (~1 L3 RTT per check).
__global__ __launch_bounds__(256, 1) void rnn_steps2(
        const ushort_t* __restrict__ Wh0b,
        const ushort_t* __restrict__ Wx1b,
        const ushort_t* __restrict__ Wh1b,
        const float* __restrict__ bh1,
        const float* __restrict__ xproj,
        ushort_t* __restrict__ h0buf,
        ushort_t* __restrict__ h1buf,
        ushort_t* __restrict__ tops,
        unsigned* __restrict__ flags) {
    const int lb = blockIdx.x;           // 0..63
    const int lane = threadIdx.x & 63;
    const int widx = threadIdx.x >> 6;
    const int quad = lane >> 4;
    const int l15 = lane & 15;
    const int wid = (lb & 31) * 4 + widx;     // 0..127 within layer
    const int nt = wid & 63, mt = wid >> 6;
    const int b0 = mt * 16 + l15;
    const int h = nt * 16 + l15;
    constexpr int BH = B_ * H_;

    if (lb < 32) {
        // ======== layer 0: h0[p] = tanh(xproj[p] + h0[p-1] @ Wh0^T) ==========
        unsigned* myflag = flags + wid;
        short8 wf[32];
        const short8* Wr = (const short8*)(Wh0b + (long)h * H_ + quad * 8);
#pragma unroll
        for (int k = 0; k < 32; ++k) wf[k] = Wr[k * 4];
        for (int p = 0; p < S_; ++p) {
            // xproj is read-only (written by an earlier dispatch): load before wait
            const float* xp = xproj + (long)p * BH;
            float xv[4];
#pragma unroll
            for (int r = 0; r < 4; ++r) xv[r] = xp[(long)(mt * 16 + quad * 4 + r) * H_ + h];
            wait2(flags, p, 0);                        // h0[p-1] complete (RAW)
            const ushort_t* Ap = h0buf + ((p + 1) & 1) * BH + (long)b0 * H_ + quad * 8;
            short8 a[32];
            ld16n(a, Ap);
            ld16n(a + 16, Ap + 512);
            WAITV; SB;
            f32x4 aA = {0.f, 0.f, 0.f, 0.f}, aB = {0.f, 0.f, 0.f, 0.f};
#pragma unroll
            for (int k = 0; k < 32; k += 2) {
                aA = __builtin_amdgcn_mfma_f32_16x16x32_bf16(a[k], wf[k], aA, 0, 0, 0);
                aB = __builtin_amdgcn_mfma_f32_16x16x32_bf16(a[k + 1], wf[k + 1], aB, 0, 0, 0);
            }
            float vv[4];
#pragma unroll
            for (int r = 0; r < 4; ++r) vv[r] = tanhf(aA[r] + aB[r] + xv[r]);
            wait2(flags, 0, p - 1);                    // WAR: layer1 done reading slot
            ushort_t* outp = h0buf + (p & 1) * BH;
#pragma unroll
            for (int r = 0; r < 4; ++r)
                st2_coh(outp + (long)(mt * 16 + quad * 4 + r) * H_ + h, (unsigned)f32_bf16(vv[r]));
            set_flag(myflag, (unsigned)(p + 1));
        }
    } else {
        // ======== layer 1: h1[t] = tanh(h0[t]@Wx1^T + h1[t-1]@Wh1^T + bh1) ===
        unsigned* myflag = flags + 128 + wid;
        short8 wfx[32], wfh[32];
        const short8* Wxr = (const short8*)(Wx1b + (long)h * H_ + quad * 8);
        const short8* Whr = (const short8*)(Wh1b + (long)h * H_ + quad * 8);
#pragma unroll
        for (int k = 0; k < 32; ++k) { wfx[k] = Wxr[k * 4]; wfh[k] = Whr[k * 4]; }
        const float bias1 = bh1[h];
        for (int t = 0; t < S_; ++t) {
            // RAW on h0[t] (flags0 >= t+1); RAW+WAR on h1[t-1]/slot (flags1 >= t)
            wait2(flags, t + 1, t);
            const ushort_t* A0 = h0buf + (t & 1) * BH + (long)b0 * H_ + quad * 8;
            const ushort_t* A1 = h1buf + ((t + 1) & 1) * BH + (long)b0 * H_ + quad * 8;
            f32x4 aA = {0.f, 0.f, 0.f, 0.f}, aB = {0.f, 0.f, 0.f, 0.f};
            {
                short8 a0[16], a1[16];
                ld16n(a0, A0); ld16n(a1, A1);
                WAITV; SB;
#pragma unroll
                for (int k = 0; k < 16; ++k) {
                    aA = __builtin_amdgcn_mfma_f32_16x16x32_bf16(a0[k], wfx[k], aA, 0, 0, 0);
                    aB = __builtin_amdgcn_mfma_f32_16x16x32_bf16(a1[k], wfh[k], aB, 0, 0, 0);
                }
            }
            {
                short8 a0[16], a1[16];
                ld16n(a0, A0 + 512); ld16n(a1, A1 + 512);
                WAITV; SB;
#pragma unroll
                for (int k = 0; k < 16; ++k) {
                    aA = __builtin_amdgcn_mfma_f32_16x16x32_bf16(a0[k], wfx[16 + k], aA, 0, 0, 0);
                    aB = __builtin_amdgcn_mfma_f32_16x16x32_bf16(a1[k], wfh[16 + k], aB, 0, 0, 0);
                }
            }
            ushort_t* outp = h1buf + (t & 1) * BH;
            ushort_t* top = tops + (long)t * BH;
#pragma unroll
            for (int r = 0; r < 4; ++r) {
                float v = tanhf(aA[r] + aB[r] + bias1);
                ushort_t bv = f32_bf16(v);
                st2_coh(outp + (long)(mt * 16 + quad * 4 + r) * H_ + h, (unsigned)bv);
                top[(long)(mt * 16 + quad * 4 + r) * H_ + h] = bv;   // normal store
            }
            set_flag(myflag, (unsigned)(t + 1));
        }
    }
}

// ---------------- final GEMM: logits = tops @ Wout^T + bout -------------------
// 128x128 tile, BK=32, 4 waves x 64x64. LDS slot-swizzle (both-sides, rule #21):
// LDS[row][slot] <- global[row][slot ^ ((row>>1)&3)]; read slot = quad ^ ((row>>1)&3).
#define BM 128
#define BN 128
#define BK 32

__device__ __forceinline__ void ld_lds16(const ushort_t* g, ushort_t* l) {
    __builtin_amdgcn_global_load_lds((const __attribute__((address_space(1))) void*)g,
                                     (__attribute__((address_space(3))) void*)l, 16, 0, 0);
}

__global__ __launch_bounds__(256) void out_gemm(const ushort_t* __restrict__ A,   // [2048,1024]
                                                const ushort_t* __restrict__ Bw,  // [32000,1024]
                                                const float* __restrict__ bout,
                                                float* __restrict__ C) {
    __shared__ __align__(16) ushort_t lA[BM * BK];  // 8KB
    __shared__ __align__(16) ushort_t lB[BN * BK];  // 8KB
    int mblk = blockIdx.x;   // 0..15
    int nblk = blockIdx.y;   // 0..249
    int tid = threadIdx.x;
    int lane = tid & 63;
    int w = tid >> 6;
    int quad = lane >> 4;
    // staging map: thread tid covers (row = tid/4, 16B slot = tid%4), pre-swizzled src
    int srow = tid >> 2;
    int sslot = (tid & 3) ^ ((srow >> 1) & 3);
    int skol = sslot * 8;
    const ushort_t* Ag = A + (long)(mblk * BM + srow) * H_ + skol;
    const ushort_t* Bg = Bw + (long)(nblk * BN + srow) * H_ + skol;
    ushort_t* lA0 = lA + tid * 8;
    ushort_t* lA1 = lA + 2048 + tid * 8;
    ushort_t* lB0 = lB + tid * 8;              // rows 0..63
    ushort_t* lB1 = lB + 2048 + tid * 8;       // rows 64..127 ((row>>1)&3 unchanged by +64)

    int msub = (w & 1) * 64;
    int nsub = (w >> 1) * 64;
    int l15 = lane & 15;
    int rquad = quad ^ ((l15 >> 1) & 3);       // swizzled read slot
    f32x4 acc[4][4];
#pragma unroll
    for (int i = 0; i < 4; ++i)
#pragma unroll
        for (int j = 0; j < 4; ++j) acc[i][j] = (f32x4){0.f, 0.f, 0.f, 0.f};

    for (int k0 = 0; k0 < H_; k0 += BK) {
        ld_lds16(Ag + k0, lA0);
        ld_lds16(Ag + 64 * H_ + k0, lA1);
        ld_lds16(Bg + k0, lB0);
        ld_lds16(Bg + 64 * H_ + k0, lB1);
        __syncthreads();
        short8 af[4], bf[4];
#pragma unroll
        for (int i = 0; i < 4; ++i)
            af[i] = *(const short8*)&lA[(msub + i * 16 + l15) * BK + rquad * 8];
#pragma unroll
        for (int j = 0; j < 4; ++j)
            bf[j] = *(const short8*)&lB[(nsub + j * 16 + l15) * BK + rquad * 8];
#pragma unroll
        for (int i = 0; i < 4; ++i)
#pragma unroll
            for (int j = 0; j < 4; ++j)
                acc[i][j] = __builtin_amdgcn_mfma_f32_16x16x32_bf16(af[i], bf[j], acc[i][j], 0, 0, 0);
        __syncthreads();
    }

#pragma unroll
    for (int j = 0; j < 4; ++j) {
        int n = nblk * BN + nsub + j * 16 + l15;
        float bo = bout[n];
#pragma unroll
        for (int i = 0; i < 4; ++i) {
#pragma unroll
            for (int r = 0; r < 4; ++r) {
                int m = mblk * BM + msub + i * 16 + quad * 4 + r;
                C[(long)m * V_ + n] = acc[i][j][r] + bo;
            }
        }
    }
}

// ---------------- final hidden: bf16 slot-1 buffers -> fp32 tail of d_out -----
__global__ void final_hidden(const ushort_t* __restrict__ h0buf,
                             const ushort_t* __restrict__ h1buf,
                             float* __restrict__ out) {
    int i = blockIdx.x * blockDim.x + threadIdx.x;  // 0 .. 2*B*H-1
    int j = i & (B_ * H_ - 1);
    // h0[63] lives in h0buf slot (63&1)=1 ; h1[63] in h1buf slot 1
    ushort_t v = (i < B_ * H_) ? h0buf[B_ * H_ + j] : h1buf[B_ * H_ + j];
    out[(long)S_ * B_ * V_ + i] = bf16_f32(v);
}

extern "C" void kernel_launch(void* const* d_in, const int* in_sizes, int n_in,
                              void* d_out, int out_size, void* d_ws, size_t ws_size,
                              hipStream_t stream) {
    const int*   tok  = (const int*)d_in[0];
    const float* hid  = (const float*)d_in[1];
    const float* emb  = (const float*)d_in[2];
    const float* Wx0  = (const float*)d_in[3];
    const float* Wh0  = (const float*)d_in[4];
    const float* bh0  = (const float*)d_in[5];
    const float* Wx1  = (const float*)d_in[6];
    const float* Wh1  = (const float*)d_in[7];
    const float* bh1  = (const float*)d_in[8];
    const float* Wout = (const float*)d_in[9];
    const float* bout = (const float*)d_in[10];
    float* out = (float*)d_out;

    char* ws = (char*)d_ws;
    size_t off = 0;
    ushort_t* woutb = (ushort_t*)(ws + off); off += (size_t)V_ * H_ * 2;       // 65,536,000
    ushort_t* wh0b  = (ushort_t*)(ws + off); off += (size_t)H_ * H_ * 2;       // 2MB
    ushort_t* wx1b  = (ushort_t*)(ws + off); off += (size_t)H_ * H_ * 2;
    ushort_t* wh1b  = (ushort_t*)(ws + off); off += (size_t)H_ * H_ * 2;
    ushort_t* wx0b  = (ushort_t*)(ws + off); off += (size_t)H_ * E_ * 2;       // 1MB
    ushort_t* xb    = (ushort_t*)(ws + off); off += (size_t)S_ * B_ * E_ * 2;  // 2MB
    float*    xproj = (float*)(ws + off);    off += (size_t)S_ * B_ * H_ * 4;  // 8MB
    ushort_t* topsb = (ushort_t*)(ws + off); off += (size_t)S_ * B_ * H_ * 2;  // 4MB
    ushort_t* h0b   = (ushort_t*)(ws + off); off += (size_t)2 * B_ * H_ * 2;
    ushort_t* h1b   = (ushort_t*)(ws + off); off += (size_t)2 * B_ * H_ * 2;
    unsigned* flags = (unsigned*)(ws + off); off += 1024;

    // weight conversions (independent, back-to-back on stream)
    cvt_bf16<<<2048, 256, 0, stream>>>(Wout, woutb, V_ * H_ / 4);
    cvt_bf16<<<256, 256, 0, stream>>>(Wh0, wh0b, H_ * H_ / 4);
    cvt_bf16<<<256, 256, 0, stream>>>(Wx1, wx1b, H_ * H_ / 4);
    cvt_bf16<<<256, 256, 0, stream>>>(Wh1, wh1b, H_ * H_ / 4);
    cvt_bf16<<<128, 256, 0, stream>>>(Wx0, wx0b, H_ * E_ / 4);
    init_hidden<<<256, 256, 0, stream>>>(hid, h0b, h1b, flags);
    gather_emb<<<S_ * B_, 128, 0, stream>>>(tok, emb, xb);
    // x-side projection for all timesteps, one GEMM
    xproj_kernel<<<2048, 256, 0, stream>>>(xb, wx0b, bh0, xproj);
    // persistent pipelined recurrence with flag-word barrier
    rnn_steps2<<<64, 256, 0, stream>>>(wh0b, wx1b, wh1b, bh1, xproj, h0b, h1b, topsb, flags);
    // output projection
    out_gemm<<<dim3(16, 250), 256, 0, stream>>>(topsb, woutb, bout, out);
    final_hidden<<<256, 256, 0, stream>>>(h0b, h1b, out);
}